// Round 4
// baseline (642.547 us; speedup 1.0000x reference)
//
#include <hip/hip_runtime.h>
#include <math.h>

#define NN 50000
#define NE 600000
#define DIM 128
#define LAYERS 3
#define BN_EPS 1e-5f

#define SC_ELE 2048
#define NSCAN ((NN + SC_ELE - 1) / SC_ELE)   // 25 scan blocks
#define TM 32

// ---------------------------------------------------------------- init ----
__global__ void k_init(int* __restrict__ deg, float* __restrict__ bnstats) {
    int i = blockIdx.x * 256 + threadIdx.x;
    if (i < NN) deg[i] = 0;
    if (i < LAYERS * 2 * DIM) bnstats[i] = 0.0f;
}

// ----------------------------------------------------------- histogram ----
__global__ void k_hist(const int* __restrict__ dst, int* __restrict__ deg) {
    int e = blockIdx.x * 256 + threadIdx.x;
    if (e < NE) atomicAdd(&deg[dst[e]], 1);
}

// ------------------------------------------- hierarchical scan, pass 1 ----
__global__ __launch_bounds__(1024) void k_scan1(const int* __restrict__ deg,
                                                int* __restrict__ part,
                                                int* __restrict__ bsum) {
    __shared__ int ws[16];
    const int t = threadIdx.x, lane = t & 63, wv = t >> 6;
    const int base = blockIdx.x * SC_ELE;
    const int e0 = base + 2 * t, e1 = e0 + 1;
    const int v0 = (e0 < NN) ? deg[e0] : 0;
    const int v1 = (e1 < NN) ? deg[e1] : 0;
    const int s = v0 + v1;
    int incl = s;
    #pragma unroll
    for (int o = 1; o < 64; o <<= 1) {
        int u = __shfl_up(incl, o);
        if (lane >= o) incl += u;
    }
    if (lane == 63) ws[wv] = incl;
    __syncthreads();
    if (wv == 0) {
        int x = (lane < 16) ? ws[lane] : 0;
        int ix = x;
        #pragma unroll
        for (int o = 1; o < 16; o <<= 1) {
            int u = __shfl_up(ix, o);
            if (lane >= o) ix += u;
        }
        if (lane < 16) ws[lane] = ix - x;          // exclusive wave offsets
        if (lane == 15) bsum[blockIdx.x] = ix;     // block total
    }
    __syncthreads();
    const int excl = incl - s + ws[wv];
    if (e0 < NN) part[e0] = excl;
    if (e1 < NN) part[e1] = excl + v0;
}

// ------------------------------------------- hierarchical scan, pass 2 ----
__global__ void k_scan2(const int* __restrict__ bsum, int* __restrict__ boff) {
    const int lane = threadIdx.x;                   // 64 threads, 1 block
    const int v = (lane < NSCAN) ? bsum[lane] : 0;
    int ix = v;
    #pragma unroll
    for (int o = 1; o < 64; o <<= 1) {
        int u = __shfl_up(ix, o);
        if (lane >= o) ix += u;
    }
    if (lane < NSCAN) boff[lane] = ix - v;
}

// --------------------------- hierarchical scan, pass 3 (+cur, +off[NN]) ----
__global__ void k_scan3(const int* __restrict__ part, const int* __restrict__ boff,
                        int* __restrict__ off, int* __restrict__ cur) {
    int i = blockIdx.x * 256 + threadIdx.x;
    if (i < NN) {
        int o = part[i] + boff[i >> 11];
        off[i] = o;
        cur[i] = o;
        if (i == 0) off[NN] = NE;
    }
}

// ------------------------------------------------------------ csr fill ----
__global__ void k_fill(const int* __restrict__ src, const int* __restrict__ dst,
                       int* __restrict__ cur, int* __restrict__ csr) {
    int e = blockIdx.x * 256 + threadIdx.x;
    if (e < NE) {
        int p = atomicAdd(&cur[dst[e]], 1);
        csr[p] = src[e];
    }
}

// ----------------------------- BN finalize: sc/sh for fused consumption ----
__global__ void k_fin(const float* __restrict__ bnsum, const float* __restrict__ bnsq,
                      const float* __restrict__ gamma, const float* __restrict__ beta,
                      float* __restrict__ scsh) {
    int j = threadIdx.x;                            // 128 threads, 1 block
    const float invN = 1.0f / (float)NN;
    float mu  = bnsum[j] * invN;
    float var = bnsq[j] * invN - mu * mu;
    float k   = rsqrtf(var + BN_EPS) * gamma[j];
    scsh[j]       = k;                              // scale
    scsh[DIM + j] = beta[j] - mu * k;               // shift
}

// ---------------- fused layer: gather(+norm+relu) -> MLP -> z + stats ----
// NORM=0: hprev is raw x. NORM=1: h = relu(hprev*sc+sh) applied per read.
// LDS: only the 16 KB z tile -> 4 blocks/CU (VGPR-capped at 128).
template <int NORM>
__global__ __launch_bounds__(256, 4) void k_layer(
        const float* __restrict__ hprev, const float* __restrict__ scsh,
        const int* __restrict__ off, const int* __restrict__ csr,
        const float* __restrict__ W1, const float* __restrict__ b1,
        const float* __restrict__ W2, const float* __restrict__ b2,
        float* __restrict__ zout,
        float* __restrict__ bnsum, float* __restrict__ bnsq) {
    __shared__ float zt[TM][DIM];   // 16 KB: A tile -> y1 tile -> stats scratch
    const int t = threadIdx.x;
    const int lane = t & 63, wv = t >> 6;
    const int c = t & 31;           // output cols 4c..4c+3
    const int r = t >> 5;           // row group: rows 4r..4r+3
    const int row0 = blockIdx.x * TM;

    // ---- phase 1: gather + (norm+relu) -> zt ----
    {
        float2 scv, shv;
        if (NORM) {
            scv = *(const float2*)&scsh[lane * 2];
            shv = *(const float2*)&scsh[DIM + lane * 2];
        }
        #pragma unroll
        for (int nb = 0; nb < 8; ++nb) {
            const int row = wv * 8 + nb;
            const int n = row0 + row;
            float2 acc = make_float2(0.f, 0.f);
            if (n < NN) {
                float2 v = *(const float2*)&hprev[(size_t)n * DIM + lane * 2];
                if (NORM) {
                    v.x = fmaxf(fmaf(v.x, scv.x, shv.x), 0.f);
                    v.y = fmaxf(fmaf(v.y, scv.y, shv.y), 0.f);
                }
                acc = v;
                const int end = off[n + 1];
                int i = off[n];
                for (; i + 1 < end; i += 2) {
                    int s0 = csr[i], s1 = csr[i + 1];
                    float2 v0 = *(const float2*)&hprev[(size_t)s0 * DIM + lane * 2];
                    float2 v1 = *(const float2*)&hprev[(size_t)s1 * DIM + lane * 2];
                    if (NORM) {
                        v0.x = fmaxf(fmaf(v0.x, scv.x, shv.x), 0.f);
                        v0.y = fmaxf(fmaf(v0.y, scv.y, shv.y), 0.f);
                        v1.x = fmaxf(fmaf(v1.x, scv.x, shv.x), 0.f);
                        v1.y = fmaxf(fmaf(v1.y, scv.y, shv.y), 0.f);
                    }
                    acc.x += v0.x + v1.x;
                    acc.y += v0.y + v1.y;
                }
                if (i < end) {
                    int s0 = csr[i];
                    float2 v0 = *(const float2*)&hprev[(size_t)s0 * DIM + lane * 2];
                    if (NORM) {
                        v0.x = fmaxf(fmaf(v0.x, scv.x, shv.x), 0.f);
                        v0.y = fmaxf(fmaf(v0.y, scv.y, shv.y), 0.f);
                    }
                    acc.x += v0.x;
                    acc.y += v0.y;
                }
            }
            *(float2*)&zt[row][lane * 2] = acc;
        }
    }
    __syncthreads();

    // ---- phase 2: GEMM1 (W1 streamed from L2) ----
    float acc[4][4];
    #pragma unroll
    for (int i = 0; i < 4; ++i)
        #pragma unroll
        for (int j = 0; j < 4; ++j) acc[i][j] = 0.0f;

    for (int k = 0; k < DIM; k += 4) {
        float4 a4[4];
        #pragma unroll
        for (int i = 0; i < 4; ++i) a4[i] = *(const float4*)&zt[r * 4 + i][k];
        #pragma unroll
        for (int kk = 0; kk < 4; ++kk) {
            const float4 b = *(const float4*)&W1[(k + kk) * DIM + c * 4];
            #pragma unroll
            for (int i = 0; i < 4; ++i) {
                const float a = (&a4[i].x)[kk];
                acc[i][0] = fmaf(a, b.x, acc[i][0]);
                acc[i][1] = fmaf(a, b.y, acc[i][1]);
                acc[i][2] = fmaf(a, b.z, acc[i][2]);
                acc[i][3] = fmaf(a, b.w, acc[i][3]);
            }
        }
    }
    __syncthreads();

    // ---- phase 3: bias1 + relu -> y1 into zt ----
    const float4 bias1 = *(const float4*)&b1[c * 4];
    #pragma unroll
    for (int i = 0; i < 4; ++i) {
        float4 y;
        y.x = fmaxf(acc[i][0] + bias1.x, 0.f);
        y.y = fmaxf(acc[i][1] + bias1.y, 0.f);
        y.z = fmaxf(acc[i][2] + bias1.z, 0.f);
        y.w = fmaxf(acc[i][3] + bias1.w, 0.f);
        *(float4*)&zt[r * 4 + i][c * 4] = y;
    }
    __syncthreads();

    // ---- phase 4: GEMM2 (W2 streamed from L2) ----
    #pragma unroll
    for (int i = 0; i < 4; ++i)
        #pragma unroll
        for (int j = 0; j < 4; ++j) acc[i][j] = 0.0f;

    for (int k = 0; k < DIM; k += 4) {
        float4 a4[4];
        #pragma unroll
        for (int i = 0; i < 4; ++i) a4[i] = *(const float4*)&zt[r * 4 + i][k];
        #pragma unroll
        for (int kk = 0; kk < 4; ++kk) {
            const float4 b = *(const float4*)&W2[(k + kk) * DIM + c * 4];
            #pragma unroll
            for (int i = 0; i < 4; ++i) {
                const float a = (&a4[i].x)[kk];
                acc[i][0] = fmaf(a, b.x, acc[i][0]);
                acc[i][1] = fmaf(a, b.y, acc[i][1]);
                acc[i][2] = fmaf(a, b.z, acc[i][2]);
                acc[i][3] = fmaf(a, b.w, acc[i][3]);
            }
        }
    }
    __syncthreads();   // zt reads done; safe to reuse as stats scratch

    // ---- phase 5: bias2, write z (pre-BN), block stats -> atomics ----
    const float4 bias2 = *(const float4*)&b2[c * 4];
    float s[4] = {0.f, 0.f, 0.f, 0.f};
    float q[4] = {0.f, 0.f, 0.f, 0.f};
    #pragma unroll
    for (int i = 0; i < 4; ++i) {
        int g = row0 + r * 4 + i;
        float4 zv;
        zv.x = acc[i][0] + bias2.x;
        zv.y = acc[i][1] + bias2.y;
        zv.z = acc[i][2] + bias2.z;
        zv.w = acc[i][3] + bias2.w;
        if (g < NN) {
            *(float4*)&zout[(size_t)g * DIM + c * 4] = zv;
            s[0] += zv.x; s[1] += zv.y; s[2] += zv.z; s[3] += zv.w;
            q[0] += zv.x * zv.x; q[1] += zv.y * zv.y;
            q[2] += zv.z * zv.z; q[3] += zv.w * zv.w;
        }
    }
    float* scratch = &zt[0][0];     // [0:1024)=sum, [1024:2048)=sq
    #pragma unroll
    for (int j = 0; j < 4; ++j) {
        scratch[r * DIM + c * 4 + j]        = s[j];
        scratch[1024 + r * DIM + c * 4 + j] = q[j];
    }
    __syncthreads();
    if (t < DIM) {
        float ss = 0.f, qq = 0.f;
        #pragma unroll
        for (int rr = 0; rr < 8; ++rr) {
            ss += scratch[rr * DIM + t];
            qq += scratch[1024 + rr * DIM + t];
        }
        atomicAdd(&bnsum[t], ss);
        atomicAdd(&bnsq[t], qq);
    }
}

// ------------------------- final FC with fused last-layer norm + relu ----
__global__ __launch_bounds__(256) void k_fc(const float* __restrict__ z,
                                            const float* __restrict__ scsh,
                                            const float* __restrict__ fc_w,
                                            const float* __restrict__ fc_b,
                                            float* __restrict__ out) {
    int wid  = (blockIdx.x * 256 + threadIdx.x) >> 6;
    int lane = threadIdx.x & 63;
    if (wid >= NN) return;
    float2 v = *(const float2*)&z[(size_t)wid * DIM + lane * 2];
    float2 scv = *(const float2*)&scsh[lane * 2];
    float2 shv = *(const float2*)&scsh[DIM + lane * 2];
    v.x = fmaxf(fmaf(v.x, scv.x, shv.x), 0.f);
    v.y = fmaxf(fmaf(v.y, scv.y, shv.y), 0.f);
    float2 wv = *(const float2*)&fc_w[lane * 2];
    float s = v.x * wv.x + v.y * wv.y;
    #pragma unroll
    for (int o = 32; o >= 1; o >>= 1) s += __shfl_down(s, o);
    if (lane == 0) out[wid] = s + fc_b[0];
}

// -------------------------------------------------------------- launch ----
extern "C" void kernel_launch(void* const* d_in, const int* in_sizes, int n_in,
                              void* d_out, int out_size, void* d_ws, size_t ws_size,
                              hipStream_t stream) {
    const float* x     = (const float*)d_in[0];
    const int*   src   = (const int*)d_in[1];          // edge_index[0]
    const int*   dst   = ((const int*)d_in[1]) + NE;   // edge_index[1]
    const float* W1    = (const float*)d_in[2];
    const float* b1    = (const float*)d_in[3];
    const float* W2    = (const float*)d_in[4];
    const float* b2    = (const float*)d_in[5];
    const float* gamma = (const float*)d_in[6];
    const float* beta  = (const float*)d_in[7];
    const float* fc_w  = (const float*)d_in[8];
    const float* fc_b  = (const float*)d_in[9];
    float* out = (float*)d_out;

    // workspace carve (16B aligned chunks)
    char* ws = (char*)d_ws;
    size_t o = 0;
    auto carve = [&](size_t bytes) {
        char* p = ws + o;
        o += (bytes + 15) & ~(size_t)15;
        return p;
    };
    int*   deg     = (int*)carve(NN * 4);
    int*   off     = (int*)carve((NN + 1) * 4);
    int*   cur     = (int*)carve(NN * 4);
    int*   csr     = (int*)carve(NE * 4);
    int*   part    = (int*)carve(NN * 4);
    int*   bsum    = (int*)carve(NSCAN * 4);
    int*   boff    = (int*)carve(NSCAN * 4);
    float* bnstats = (float*)carve(LAYERS * 2 * DIM * 4);  // [sum(3x128) | sq(3x128)]
    float* scsh    = (float*)carve(LAYERS * 2 * DIM * 4);  // per layer [sc|sh]
    float* zA      = (float*)carve((size_t)NN * DIM * 4);
    float* zB      = (float*)carve((size_t)NN * DIM * 4);

    // ---- CSR build (once per call) ----
    k_init<<<(NN + 255) / 256, 256, 0, stream>>>(deg, bnstats);
    k_hist<<<(NE + 255) / 256, 256, 0, stream>>>(dst, deg);
    k_scan1<<<NSCAN, 1024, 0, stream>>>(deg, part, bsum);
    k_scan2<<<1, 64, 0, stream>>>(bsum, boff);
    k_scan3<<<(NN + 255) / 256, 256, 0, stream>>>(part, boff, off, cur);
    k_fill<<<(NE + 255) / 256, 256, 0, stream>>>(src, dst, cur, csr);

    // ---- fused layers ----
    const int nblk = (NN + TM - 1) / TM;
    float* zbuf[2] = {zA, zB};
    for (int l = 0; l < LAYERS; ++l) {
        const float* hin = (l == 0) ? x : zbuf[(l + 1) & 1];
        float* zo = zbuf[l & 1];
        float* sum_l = bnstats + l * DIM;
        float* sq_l  = bnstats + LAYERS * DIM + l * DIM;
        float* scsh_prev = scsh + (l - 1) * 2 * DIM;
        if (l == 0)
            k_layer<0><<<nblk, 256, 0, stream>>>(hin, nullptr, off, csr,
                                                 W1, b1, W2, b2, zo, sum_l, sq_l);
        else
            k_layer<1><<<nblk, 256, 0, stream>>>(hin, scsh_prev, off, csr,
                                                 W1 + (size_t)l * DIM * DIM, b1 + l * DIM,
                                                 W2 + (size_t)l * DIM * DIM, b2 + l * DIM,
                                                 zo, sum_l, sq_l);
        k_fin<<<1, 128, 0, stream>>>(sum_l, sq_l, gamma + l * DIM, beta + l * DIM,
                                     scsh + l * 2 * DIM);
    }

    // ---- final FC (fused last norm) ----
    k_fc<<<(NN * 64 + 255) / 256, 256, 0, stream>>>(zbuf[(LAYERS + 1) & 1],
                                                    scsh + (LAYERS - 1) * 2 * DIM,
                                                    fc_w, fc_b, out);
}

// Round 5
// 608.197 us; speedup vs baseline: 1.0565x; 1.0565x over previous
//
#include <hip/hip_runtime.h>
#include <math.h>

#define NN 50000
#define NE 600000
#define DIM 128
#define LAYERS 3
#define BN_EPS 1e-5f

#define SC_ELE 2048
#define NSCAN ((NN + SC_ELE - 1) / SC_ELE)   // 25 scan blocks
#define TM 32

// ---------------------------------------------------------------- init ----
__global__ void k_init(int* __restrict__ deg, float* __restrict__ bnstats) {
    int i = blockIdx.x * 256 + threadIdx.x;
    if (i < NN) deg[i] = 0;
    if (i < LAYERS * 2 * DIM) bnstats[i] = 0.0f;
}

// ----------------------------------------------------------- histogram ----
__global__ void k_hist(const int* __restrict__ dst, int* __restrict__ deg) {
    int e = blockIdx.x * 256 + threadIdx.x;
    if (e < NE) atomicAdd(&deg[dst[e]], 1);
}

// ------------------------------------------- hierarchical scan, pass 1 ----
__global__ __launch_bounds__(1024) void k_scan1(const int* __restrict__ deg,
                                                int* __restrict__ part,
                                                int* __restrict__ bsum) {
    __shared__ int ws[16];
    const int t = threadIdx.x, lane = t & 63, wv = t >> 6;
    const int base = blockIdx.x * SC_ELE;
    const int e0 = base + 2 * t, e1 = e0 + 1;
    const int v0 = (e0 < NN) ? deg[e0] : 0;
    const int v1 = (e1 < NN) ? deg[e1] : 0;
    const int s = v0 + v1;
    int incl = s;
    #pragma unroll
    for (int o = 1; o < 64; o <<= 1) {
        int u = __shfl_up(incl, o);
        if (lane >= o) incl += u;
    }
    if (lane == 63) ws[wv] = incl;
    __syncthreads();
    if (wv == 0) {
        int x = (lane < 16) ? ws[lane] : 0;
        int ix = x;
        #pragma unroll
        for (int o = 1; o < 16; o <<= 1) {
            int u = __shfl_up(ix, o);
            if (lane >= o) ix += u;
        }
        if (lane < 16) ws[lane] = ix - x;          // exclusive wave offsets
        if (lane == 15) bsum[blockIdx.x] = ix;     // block total
    }
    __syncthreads();
    const int excl = incl - s + ws[wv];
    if (e0 < NN) part[e0] = excl;
    if (e1 < NN) part[e1] = excl + v0;
}

// ------------------------------------------- hierarchical scan, pass 2 ----
__global__ void k_scan2(const int* __restrict__ bsum, int* __restrict__ boff) {
    const int lane = threadIdx.x;                   // 64 threads, 1 block
    const int v = (lane < NSCAN) ? bsum[lane] : 0;
    int ix = v;
    #pragma unroll
    for (int o = 1; o < 64; o <<= 1) {
        int u = __shfl_up(ix, o);
        if (lane >= o) ix += u;
    }
    if (lane < NSCAN) boff[lane] = ix - v;
}

// --------------------------- hierarchical scan, pass 3 (+cur, +off[NN]) ----
__global__ void k_scan3(const int* __restrict__ part, const int* __restrict__ boff,
                        int* __restrict__ off, int* __restrict__ cur) {
    int i = blockIdx.x * 256 + threadIdx.x;
    if (i < NN) {
        int o = part[i] + boff[i >> 11];
        off[i] = o;
        cur[i] = o;
        if (i == 0) off[NN] = NE;
    }
}

// ------------------------------------------------------------ csr fill ----
__global__ void k_fill(const int* __restrict__ src, const int* __restrict__ dst,
                       int* __restrict__ cur, int* __restrict__ csr) {
    int e = blockIdx.x * 256 + threadIdx.x;
    if (e < NE) {
        int p = atomicAdd(&cur[dst[e]], 1);
        csr[p] = src[e];
    }
}

// ---------------- aggregate: a = f(h) + sum_in f(h), f = norm+relu ------
// NORM=0: f = identity (input is raw x). NORM=1: f(v)=relu(v*sc+sh), with
// (sc,sh) recomputed per lane from prev layer's stats (bit-identical to a
// separate finalize pass). One wave per node; lane owns cols 2l,2l+1.
template <int NORM>
__global__ __launch_bounds__(256) void k_agg(const float* __restrict__ h,
                                             const float* __restrict__ bnsum,
                                             const float* __restrict__ bnsq,
                                             const float* __restrict__ gamma,
                                             const float* __restrict__ beta,
                                             const int* __restrict__ off,
                                             const int* __restrict__ csr,
                                             float* __restrict__ a) {
    int wid  = (blockIdx.x * 256 + threadIdx.x) >> 6;
    int lane = threadIdx.x & 63;
    if (wid >= NN) return;

    float2 scv = make_float2(1.f, 0.f), shv = make_float2(0.f, 0.f);
    if (NORM) {
        const int j0 = lane * 2;
        const float invN = 1.0f / (float)NN;
        float mu0 = bnsum[j0] * invN;
        float mu1 = bnsum[j0 + 1] * invN;
        float k0 = rsqrtf(bnsq[j0] * invN - mu0 * mu0 + BN_EPS) * gamma[j0];
        float k1 = rsqrtf(bnsq[j0 + 1] * invN - mu1 * mu1 + BN_EPS) * gamma[j0 + 1];
        scv = make_float2(k0, k1);
        shv = make_float2(beta[j0] - mu0 * k0, beta[j0 + 1] - mu1 * k1);
    }

    const int start = off[wid], end = off[wid + 1];
    float2 v = *(const float2*)&h[(size_t)wid * DIM + lane * 2];
    float2 acc;
    if (NORM) {
        acc.x = fmaxf(fmaf(v.x, scv.x, shv.x), 0.f);
        acc.y = fmaxf(fmaf(v.y, scv.y, shv.y), 0.f);
    } else {
        acc = v;
    }
    int i = start;
    for (; i + 1 < end; i += 2) {           // unroll-2: two loads in flight
        int s0 = csr[i], s1 = csr[i + 1];
        float2 v0 = *(const float2*)&h[(size_t)s0 * DIM + lane * 2];
        float2 v1 = *(const float2*)&h[(size_t)s1 * DIM + lane * 2];
        if (NORM) {
            v0.x = fmaxf(fmaf(v0.x, scv.x, shv.x), 0.f);
            v0.y = fmaxf(fmaf(v0.y, scv.y, shv.y), 0.f);
            v1.x = fmaxf(fmaf(v1.x, scv.x, shv.x), 0.f);
            v1.y = fmaxf(fmaf(v1.y, scv.y, shv.y), 0.f);
        }
        acc.x += v0.x + v1.x;
        acc.y += v0.y + v1.y;
    }
    if (i < end) {
        int s0 = csr[i];
        float2 v0 = *(const float2*)&h[(size_t)s0 * DIM + lane * 2];
        if (NORM) {
            v0.x = fmaxf(fmaf(v0.x, scv.x, shv.x), 0.f);
            v0.y = fmaxf(fmaf(v0.y, scv.y, shv.y), 0.f);
        }
        acc.x += v0.x;
        acc.y += v0.y;
    }
    *(float2*)&a[(size_t)wid * DIM + lane * 2] = acc;
}

// -------------------- MLP in-place: z = relu(zW1+b1)W2+b2, + BN stats ----
// W1/W2 streamed from L2 (64 KB, shared by all blocks). LDS = 16 KB z tile
// -> occupancy VGPR-bound (~5 blocks/CU) instead of LDS-bound (2).
__global__ __launch_bounds__(256, 4) void k_mlp(float* __restrict__ z,
                                                const float* __restrict__ W1,
                                                const float* __restrict__ b1,
                                                const float* __restrict__ W2,
                                                const float* __restrict__ b2,
                                                float* __restrict__ bnsum,
                                                float* __restrict__ bnsq) {
    __shared__ float zt[TM][DIM];   // 16 KB: A tile -> y1 tile -> stats scratch
    const int t = threadIdx.x;
    const int c = t & 31;           // output cols 4c..4c+3
    const int r = t >> 5;           // row group: rows 4r..4r+3
    const int row0 = blockIdx.x * TM;

    // ---- load z tile ----
    #pragma unroll
    for (int i = 0; i < 4; ++i) {
        int f4 = t + i * 256;
        int rr = f4 >> 5, c4 = f4 & 31;
        int g  = row0 + rr;
        float4 v = make_float4(0.f, 0.f, 0.f, 0.f);
        if (g < NN) v = *(const float4*)&z[(size_t)g * DIM + c4 * 4];
        *(float4*)&zt[rr][c4 * 4] = v;
    }
    __syncthreads();

    // ---- GEMM1 (W1 from L2) ----
    float acc[4][4];
    #pragma unroll
    for (int i = 0; i < 4; ++i)
        #pragma unroll
        for (int j = 0; j < 4; ++j) acc[i][j] = 0.0f;

    for (int k = 0; k < DIM; k += 4) {
        float4 a4[4];
        #pragma unroll
        for (int i = 0; i < 4; ++i) a4[i] = *(const float4*)&zt[r * 4 + i][k];
        #pragma unroll
        for (int kk = 0; kk < 4; ++kk) {
            const float4 b = *(const float4*)&W1[(k + kk) * DIM + c * 4];
            #pragma unroll
            for (int i = 0; i < 4; ++i) {
                const float a = (&a4[i].x)[kk];
                acc[i][0] = fmaf(a, b.x, acc[i][0]);
                acc[i][1] = fmaf(a, b.y, acc[i][1]);
                acc[i][2] = fmaf(a, b.z, acc[i][2]);
                acc[i][3] = fmaf(a, b.w, acc[i][3]);
            }
        }
    }
    __syncthreads();

    // ---- bias1 + relu -> y1 into zt ----
    const float4 bias1 = *(const float4*)&b1[c * 4];
    #pragma unroll
    for (int i = 0; i < 4; ++i) {
        float4 y;
        y.x = fmaxf(acc[i][0] + bias1.x, 0.f);
        y.y = fmaxf(acc[i][1] + bias1.y, 0.f);
        y.z = fmaxf(acc[i][2] + bias1.z, 0.f);
        y.w = fmaxf(acc[i][3] + bias1.w, 0.f);
        *(float4*)&zt[r * 4 + i][c * 4] = y;
    }
    __syncthreads();

    // ---- GEMM2 (W2 from L2) ----
    #pragma unroll
    for (int i = 0; i < 4; ++i)
        #pragma unroll
        for (int j = 0; j < 4; ++j) acc[i][j] = 0.0f;

    for (int k = 0; k < DIM; k += 4) {
        float4 a4[4];
        #pragma unroll
        for (int i = 0; i < 4; ++i) a4[i] = *(const float4*)&zt[r * 4 + i][k];
        #pragma unroll
        for (int kk = 0; kk < 4; ++kk) {
            const float4 b = *(const float4*)&W2[(k + kk) * DIM + c * 4];
            #pragma unroll
            for (int i = 0; i < 4; ++i) {
                const float a = (&a4[i].x)[kk];
                acc[i][0] = fmaf(a, b.x, acc[i][0]);
                acc[i][1] = fmaf(a, b.y, acc[i][1]);
                acc[i][2] = fmaf(a, b.z, acc[i][2]);
                acc[i][3] = fmaf(a, b.w, acc[i][3]);
            }
        }
    }
    __syncthreads();   // zt reads done; safe to reuse as stats scratch

    // ---- bias2, write z (pre-BN) in place, block stats -> atomics ----
    const float4 bias2 = *(const float4*)&b2[c * 4];
    float s[4] = {0.f, 0.f, 0.f, 0.f};
    float q[4] = {0.f, 0.f, 0.f, 0.f};
    #pragma unroll
    for (int i = 0; i < 4; ++i) {
        int g = row0 + r * 4 + i;
        float4 zv;
        zv.x = acc[i][0] + bias2.x;
        zv.y = acc[i][1] + bias2.y;
        zv.z = acc[i][2] + bias2.z;
        zv.w = acc[i][3] + bias2.w;
        if (g < NN) {
            *(float4*)&z[(size_t)g * DIM + c * 4] = zv;
            s[0] += zv.x; s[1] += zv.y; s[2] += zv.z; s[3] += zv.w;
            q[0] += zv.x * zv.x; q[1] += zv.y * zv.y;
            q[2] += zv.z * zv.z; q[3] += zv.w * zv.w;
        }
    }
    float* scratch = &zt[0][0];     // [0:1024)=sum, [1024:2048)=sq
    #pragma unroll
    for (int j = 0; j < 4; ++j) {
        scratch[r * DIM + c * 4 + j]        = s[j];
        scratch[1024 + r * DIM + c * 4 + j] = q[j];
    }
    __syncthreads();
    if (t < DIM) {
        float ss = 0.f, qq = 0.f;
        #pragma unroll
        for (int rr = 0; rr < 8; ++rr) {
            ss += scratch[rr * DIM + t];
            qq += scratch[1024 + rr * DIM + t];
        }
        atomicAdd(&bnsum[t], ss);
        atomicAdd(&bnsq[t], qq);
    }
}

// ------------- final FC with fused last-layer norm (per-lane sc/sh) ----
__global__ __launch_bounds__(256) void k_fc(const float* __restrict__ z,
                                            const float* __restrict__ bnsum,
                                            const float* __restrict__ bnsq,
                                            const float* __restrict__ gamma,
                                            const float* __restrict__ beta,
                                            const float* __restrict__ fc_w,
                                            const float* __restrict__ fc_b,
                                            float* __restrict__ out) {
    int wid  = (blockIdx.x * 256 + threadIdx.x) >> 6;
    int lane = threadIdx.x & 63;
    if (wid >= NN) return;
    const int j0 = lane * 2;
    const float invN = 1.0f / (float)NN;
    float mu0 = bnsum[j0] * invN;
    float mu1 = bnsum[j0 + 1] * invN;
    float k0 = rsqrtf(bnsq[j0] * invN - mu0 * mu0 + BN_EPS) * gamma[j0];
    float k1 = rsqrtf(bnsq[j0 + 1] * invN - mu1 * mu1 + BN_EPS) * gamma[j0 + 1];
    float sh0 = beta[j0] - mu0 * k0;
    float sh1 = beta[j0 + 1] - mu1 * k1;

    float2 v = *(const float2*)&z[(size_t)wid * DIM + lane * 2];
    v.x = fmaxf(fmaf(v.x, k0, sh0), 0.f);
    v.y = fmaxf(fmaf(v.y, k1, sh1), 0.f);
    float2 wv = *(const float2*)&fc_w[lane * 2];
    float s = v.x * wv.x + v.y * wv.y;
    #pragma unroll
    for (int o = 32; o >= 1; o >>= 1) s += __shfl_down(s, o);
    if (lane == 0) out[wid] = s + fc_b[0];
}

// -------------------------------------------------------------- launch ----
extern "C" void kernel_launch(void* const* d_in, const int* in_sizes, int n_in,
                              void* d_out, int out_size, void* d_ws, size_t ws_size,
                              hipStream_t stream) {
    const float* x     = (const float*)d_in[0];
    const int*   src   = (const int*)d_in[1];          // edge_index[0]
    const int*   dst   = ((const int*)d_in[1]) + NE;   // edge_index[1]
    const float* W1    = (const float*)d_in[2];
    const float* b1    = (const float*)d_in[3];
    const float* W2    = (const float*)d_in[4];
    const float* b2    = (const float*)d_in[5];
    const float* gamma = (const float*)d_in[6];
    const float* beta  = (const float*)d_in[7];
    const float* fc_w  = (const float*)d_in[8];
    const float* fc_b  = (const float*)d_in[9];
    float* out = (float*)d_out;

    // workspace carve (16B aligned chunks)
    char* ws = (char*)d_ws;
    size_t o = 0;
    auto carve = [&](size_t bytes) {
        char* p = ws + o;
        o += (bytes + 15) & ~(size_t)15;
        return p;
    };
    int*   deg     = (int*)carve(NN * 4);
    int*   off     = (int*)carve((NN + 1) * 4);
    int*   cur     = (int*)carve(NN * 4);
    int*   csr     = (int*)carve(NE * 4);
    int*   part    = (int*)carve(NN * 4);
    int*   bsum    = (int*)carve(NSCAN * 4);
    int*   boff    = (int*)carve(NSCAN * 4);
    float* bnstats = (float*)carve(LAYERS * 2 * DIM * 4);  // [sum(3x128) | sq(3x128)]
    float* zA      = (float*)carve((size_t)NN * DIM * 4);
    float* zB      = (float*)carve((size_t)NN * DIM * 4);

    // ---- CSR build (once per call) ----
    k_init<<<(NN + 255) / 256, 256, 0, stream>>>(deg, bnstats);
    k_hist<<<(NE + 255) / 256, 256, 0, stream>>>(dst, deg);
    k_scan1<<<NSCAN, 1024, 0, stream>>>(deg, part, bsum);
    k_scan2<<<1, 64, 0, stream>>>(bsum, boff);
    k_scan3<<<(NN + 255) / 256, 256, 0, stream>>>(part, boff, off, cur);
    k_fill<<<(NE + 255) / 256, 256, 0, stream>>>(src, dst, cur, csr);

    // ---- layers: agg(norm-fused) -> mlp(in-place) ----
    const int nblk_mlp = (NN + TM - 1) / TM;
    const int nblk_agg = (NN * 64 + 255) / 256;
    float* zbuf[2] = {zA, zB};
    for (int l = 0; l < LAYERS; ++l) {
        const float* hin = (l == 0) ? x : zbuf[(l + 1) & 1];
        float* zo = zbuf[l & 1];
        float* sum_l = bnstats + l * DIM;
        float* sq_l  = bnstats + LAYERS * DIM + l * DIM;
        const float* sum_p = bnstats + (l - 1) * DIM;
        const float* sq_p  = bnstats + LAYERS * DIM + (l - 1) * DIM;
        if (l == 0)
            k_agg<0><<<nblk_agg, 256, 0, stream>>>(hin, nullptr, nullptr, nullptr,
                                                   nullptr, off, csr, zo);
        else
            k_agg<1><<<nblk_agg, 256, 0, stream>>>(hin, sum_p, sq_p,
                                                   gamma + (l - 1) * DIM,
                                                   beta + (l - 1) * DIM,
                                                   off, csr, zo);
        k_mlp<<<nblk_mlp, 256, 0, stream>>>(zo,
                                            W1 + (size_t)l * DIM * DIM, b1 + l * DIM,
                                            W2 + (size_t)l * DIM * DIM, b2 + l * DIM,
                                            sum_l, sq_l);
    }

    // ---- final FC (fused last norm) ----
    k_fc<<<(NN * 64 + 255) / 256, 256, 0, stream>>>(zbuf[(LAYERS + 1) & 1],
                                                    bnstats + (LAYERS - 1) * DIM,
                                                    bnstats + (2 * LAYERS - 1) * DIM,
                                                    gamma + (LAYERS - 1) * DIM,
                                                    beta + (LAYERS - 1) * DIM,
                                                    fc_w, fc_b, out);
}